// Round 3
// baseline (327.053 us; speedup 1.0000x reference)
//
#include <hip/hip_runtime.h>
#include <hip/hip_cooperative_groups.h>

namespace cg = cooperative_groups;

#define KDIM 4096   // rows of x (= both i and j extents)
#define NDIM 1024   // feature dim
#define ALPHA 0.2f
#define LOG2E 1.4426950408889634f
#define CCH 256     // chunks over sorted rank axis
#define RCH 16      // ranks per chunk
#define PFL 256     // LDS-staged (F1,F2) entries per block (fallback to global beyond)

// Sorted-prefix decomposition (exact): sort j by s2 desc (permutation sigma);
// sel(i,j) <=> rank(j) < t_i.
//   h_i = [F1_i*A1[t_i] + F2_i*(A2tot-A2[t_i])] / Z_i
//   Z_i =  F1_i*z1[t_i] + F2_i*(z2tot-z2[t_i])
__device__ __align__(16) float g_s1L[KDIM];
__device__ __align__(16) float g_s2L[KDIM];
__device__ __align__(16) float g_E [2 * KDIM];        // interleaved (E1_j, E2_j)
__device__ __align__(16) float g_F1[KDIM];
__device__ __align__(16) float g_F2[KDIM];
__device__ __align__(16) int   g_t  [KDIM];           // t_i = #{j: s2_j >= -s1_i}
__device__ __align__(16) int   g_sig[KDIM];           // rank -> j
__device__ __align__(16) float g_cs [CCH][2 * NDIM];  // chunk sums   (S1 | S2)  2 MB
__device__ __align__(16) float g_pre[CCH][2 * NDIM];  // excl. prefix (S1 | S2)  2 MB
__device__ __align__(16) float g_tot[2 * NDIM];       // column totals
__device__ __align__(16) float g_cz [2 * CCH];        // scalar chunk sums (z1,z2)
__device__ __align__(16) float g_zpre[2 * CCH];       // scalar excl. prefix
__device__ __align__(16) float g_ztot[2];             // scalar totals

// ================= fused cooperative kernel: all 5 phases, 4 grid syncs ======
// 256 blocks x 256 threads = 1 block/CU (co-residency guaranteed).
// Phase C caches its 16 gathered x-rows in registers; phase E reuses them.
__global__ __launch_bounds__(256) void k_fused(const float* __restrict__ x,
                                               const float* __restrict__ w,
                                               float* __restrict__ out){
  cg::grid_group grid = cg::this_grid();
  __shared__ __align__(16) union {
    float s2s[KDIM];                                    // phase B: 16 KB
    struct { float TL[CCH][32]; float SS[8][32]; } d;   // phase D: 33 KB
    struct {
      int    js[RCH];
      float  e1s[RCH], e2s[RCH];
      int    cnt[RCH + 1], off[RCH + 2], pos[RCH + 1];
      int    ilist[KDIM];                               // 16 KB worst-case safe
      float2 pfl[PFL];
    } e;                                                // phases C/E: ~19 KB
  } sh;
  const int tid = threadIdx.x, lane = tid & 63, wv = tid >> 6;
  const int bid = blockIdx.x;

  // ---- phase A: s1/s2 dots + row-local E/F. 1024 waves x 4 rows. ----
  {
    float4 W1r[4], W2r[4];
    #pragma unroll
    for (int q = 0; q < 4; ++q){
      const int o = q * 256 + lane * 4;
      W1r[q] = *(const float4*)(w + o);
      W2r[q] = *(const float4*)(w + NDIM + o);
    }
    const int wgid = bid * 4 + wv;
    #pragma unroll
    for (int rr = 0; rr < 4; ++rr){
      const int row = wgid * 4 + rr;
      const float* xr = x + (size_t)row * NDIM;
      float d1 = 0.f, d2 = 0.f;
      #pragma unroll
      for (int q = 0; q < 4; ++q){
        const float4 X = *(const float4*)(xr + q * 256 + lane * 4);
        d1 = fmaf(X.x, W1r[q].x, fmaf(X.y, W1r[q].y, fmaf(X.z, W1r[q].z, fmaf(X.w, W1r[q].w, d1))));
        d2 = fmaf(X.x, W2r[q].x, fmaf(X.y, W2r[q].y, fmaf(X.z, W2r[q].z, fmaf(X.w, W2r[q].w, d2))));
      }
      #pragma unroll
      for (int m = 32; m >= 1; m >>= 1){
        d1 += __shfl_xor(d1, m, 64);
        d2 += __shfl_xor(d2, m, 64);
      }
      if (lane == 0){
        const float s1 = d1 * LOG2E, s2 = d2 * LOG2E;
        g_s1L[row] = s1;
        g_s2L[row] = s2;
        g_E[2 * row]     = __builtin_amdgcn_exp2f(s2);
        g_E[2 * row + 1] = __builtin_amdgcn_exp2f(ALPHA * s2);
        g_F1[row] = __builtin_amdgcn_exp2f(s1);
        g_F2[row] = __builtin_amdgcn_exp2f(ALPHA * s1);
      }
    }
  }
  __threadfence();
  grid.sync();

  // ---- phase B: ranks + t_i counts. 32 outputs/block (2 passes of 16). ----
  {
    #pragma unroll
    for (int q = 0; q < 4; ++q)
      ((float4*)sh.s2s)[q * 256 + tid] = ((const float4*)g_s2L)[q * 256 + tid];
    __syncthreads();
    const int grp = tid >> 4, sub = tid & 15;
    #pragma unroll
    for (int pass = 0; pass < 2; ++pass){
      const int o = bid * 32 + pass * 16 + grp;     // 0..8191
      int cnt = 0;
      if (o < KDIM){
        const float val = sh.s2s[o];
        #pragma unroll 4
        for (int m = 0; m < 64; ++m){
          const int q4 = m * 16 + sub;
          const float4 v4 = ((const float4*)sh.s2s)[q4];
          const int j0 = q4 * 4;
          cnt += (v4.x > val || (v4.x == val && (j0    ) < o));
          cnt += (v4.y > val || (v4.y == val && (j0 + 1) < o));
          cnt += (v4.z > val || (v4.z == val && (j0 + 2) < o));
          cnt += (v4.w > val || (v4.w == val && (j0 + 3) < o));
        }
      } else {
        const float thr = -g_s1L[o - KDIM];
        #pragma unroll 4
        for (int m = 0; m < 64; ++m){
          const int q4 = m * 16 + sub;
          const float4 v4 = ((const float4*)sh.s2s)[q4];
          cnt += (v4.x >= thr) + (v4.y >= thr) + (v4.z >= thr) + (v4.w >= thr);
        }
      }
      cnt += __shfl_xor(cnt, 1, 64); cnt += __shfl_xor(cnt, 2, 64);
      cnt += __shfl_xor(cnt, 4, 64); cnt += __shfl_xor(cnt, 8, 64);
      if (sub == 0){
        if (o < KDIM) g_sig[cnt] = o;
        else          g_t[o - KDIM] = cnt;
      }
    }
  }
  __threadfence();
  grid.sync();

  // ---- phase C: chunk sums; x rows cached in regs for phase E. ----
  float4 v[RCH];
  {
    const int c = bid;
    if (tid < RCH){
      const int j = g_sig[c * RCH + tid];
      sh.e.js[tid]  = j;
      sh.e.e1s[tid] = g_E[2 * j];
      sh.e.e2s[tid] = g_E[2 * j + 1];
    }
    __syncthreads();
    if (tid == 0){
      float a = 0.f, b = 0.f;
      #pragma unroll
      for (int r = 0; r < RCH; ++r){ a += sh.e.e1s[r]; b += sh.e.e2s[r]; }
      g_cz[2 * c] = a; g_cz[2 * c + 1] = b;
    }
    #pragma unroll
    for (int r = 0; r < RCH; ++r)
      v[r] = *(const float4*)(x + (size_t)sh.e.js[r] * NDIM + tid * 4);
    float4 a1 = {0.f,0.f,0.f,0.f}, a2 = {0.f,0.f,0.f,0.f};
    #pragma unroll
    for (int r = 0; r < RCH; ++r){
      const float e1 = sh.e.e1s[r], e2 = sh.e.e2s[r];
      const float4 xv = v[r];
      a1.x = fmaf(e1, xv.x, a1.x); a1.y = fmaf(e1, xv.y, a1.y);
      a1.z = fmaf(e1, xv.z, a1.z); a1.w = fmaf(e1, xv.w, a1.w);
      a2.x = fmaf(e2, xv.x, a2.x); a2.y = fmaf(e2, xv.y, a2.y);
      a2.z = fmaf(e2, xv.z, a2.z); a2.w = fmaf(e2, xv.w, a2.w);
    }
    *(float4*)&g_cs[c][tid * 4]        = a1;
    *(float4*)&g_cs[c][NDIM + tid * 4] = a2;
  }
  __threadfence();
  grid.sync();

  // ---- phase D: chunk-scan (blocks 0..63, 32 cols each) + z-scan (block 64). ----
  if (bid < 64){
    const int s = tid >> 5, k2 = tid & 31;
    const int col = bid * 32 + k2;
    float run = 0.f;
    #pragma unroll 8
    for (int m = 0; m < 32; ++m){
      const float vv = g_cs[s * 32 + m][col];
      sh.d.TL[s * 32 + m][k2] = vv;
      run += vv;
    }
    sh.d.SS[s][k2] = run;
    __syncthreads();
    if (s == 0){
      float acc = 0.f;
      #pragma unroll
      for (int t = 0; t < 8; ++t){
        const float vv = sh.d.SS[t][k2];
        sh.d.SS[t][k2] = acc;
        acc += vv;
      }
      g_tot[col] = acc;
    }
    __syncthreads();
    run = sh.d.SS[s][k2];
    #pragma unroll 8
    for (int m = 0; m < 32; ++m){
      g_pre[s * 32 + m][col] = run;
      run += sh.d.TL[s * 32 + m][k2];
    }
  } else if (bid == 64 && tid < 64){
    float v1[4], v2[4];
    #pragma unroll
    for (int q = 0; q < 4; ++q){
      v1[q] = g_cz[2 * (tid * 4 + q)];
      v2[q] = g_cz[2 * (tid * 4 + q) + 1];
    }
    const float s1 = v1[0] + v1[1] + v1[2] + v1[3];
    const float s2 = v2[0] + v2[1] + v2[2] + v2[3];
    float i1 = s1, i2 = s2;
    #pragma unroll
    for (int d = 1; d < 64; d <<= 1){
      const float t1 = __shfl_up(i1, d, 64);
      const float t2 = __shfl_up(i2, d, 64);
      if (tid >= d){ i1 += t1; i2 += t2; }
    }
    float e1 = i1 - s1, e2 = i2 - s2;
    #pragma unroll
    for (int q = 0; q < 4; ++q){
      g_zpre[2 * (tid * 4 + q)]     = e1;
      g_zpre[2 * (tid * 4 + q) + 1] = e2;
      e1 += v1[q]; e2 += v2[q];
    }
    if (tid == 63){ g_ztot[0] = e1; g_ztot[1] = e2; }
  }
  __threadfence();
  grid.sync();

  // ---- phase E: in-chunk walk + emit (Z inline), x rows from register cache. ----
  {
    const int c = bid;
    const bool last = (c == CCH - 1);
    const int nbuck = last ? RCH + 1 : RCH;
    if (tid < RCH){
      const int j = g_sig[c * RCH + tid];
      sh.e.js[tid]  = j;
      sh.e.e1s[tid] = g_E[2 * j];
      sh.e.e2s[tid] = g_E[2 * j + 1];
    }
    if (tid <= RCH) sh.e.cnt[tid] = 0;
    __syncthreads();
    const int tbase = c * RCH;
    int myr[16];
    #pragma unroll
    for (int q = 0; q < 16; ++q){
      const int i = q * 256 + tid;
      const int t = g_t[i];
      const int r = t - tbase;
      const bool in = (r >= 0) && (r < nbuck);
      myr[q] = in ? r : -1;
      if (in) atomicAdd(&sh.e.cnt[r], 1);
    }
    __syncthreads();
    if (tid == 0){
      int run = 0;
      #pragma unroll
      for (int r = 0; r <= RCH; ++r){
        const int vv = sh.e.cnt[r];
        sh.e.off[r] = run; sh.e.pos[r] = run;
        run += vv;
      }
      sh.e.off[RCH + 1] = run;
    }
    __syncthreads();
    #pragma unroll
    for (int q = 0; q < 16; ++q){
      if (myr[q] >= 0){
        const int i = q * 256 + tid;
        const int p = atomicAdd(&sh.e.pos[myr[q]], 1);
        sh.e.ilist[p] = i;
        if (p < PFL) sh.e.pfl[p] = make_float2(g_F1[i], g_F2[i]);
      }
    }
    __syncthreads();

    float4 a1 = *(const float4*)&g_pre[c][tid * 4];
    float4 a2 = *(const float4*)&g_pre[c][NDIM + tid * 4];
    const float4 t2 = *(const float4*)&g_tot[NDIM + tid * 4];
    float za1 = g_zpre[2 * c], za2 = g_zpre[2 * c + 1];
    const float zt2 = g_ztot[1];

    #pragma unroll
    for (int r = 0; r < RCH; ++r){
      for (int e = sh.e.off[r]; e < sh.e.off[r + 1]; ++e){
        const int i = sh.e.ilist[e];
        float F1, F2;
        if (e < PFL){ const float2 pf = sh.e.pfl[e]; F1 = pf.x; F2 = pf.y; }
        else        { F1 = g_F1[i]; F2 = g_F2[i]; }
        const float rz = 1.0f / fmaf(F1, za1, F2 * (zt2 - za2));
        float4 h;
        h.x = fmaf(F1, a1.x, F2 * (t2.x - a2.x)) * rz;
        h.y = fmaf(F1, a1.y, F2 * (t2.y - a2.y)) * rz;
        h.z = fmaf(F1, a1.z, F2 * (t2.z - a2.z)) * rz;
        h.w = fmaf(F1, a1.w, F2 * (t2.w - a2.w)) * rz;
        *(float4*)(out + (size_t)i * NDIM + tid * 4) = h;
      }
      const float e1 = sh.e.e1s[r], e2 = sh.e.e2s[r];
      za1 += e1; za2 += e2;
      const float4 xv = v[r];
      a1.x = fmaf(e1, xv.x, a1.x); a1.y = fmaf(e1, xv.y, a1.y);
      a1.z = fmaf(e1, xv.z, a1.z); a1.w = fmaf(e1, xv.w, a1.w);
      a2.x = fmaf(e2, xv.x, a2.x); a2.y = fmaf(e2, xv.y, a2.y);
      a2.z = fmaf(e2, xv.z, a2.z); a2.w = fmaf(e2, xv.w, a2.w);
    }
    if (last){
      for (int e = sh.e.off[RCH]; e < sh.e.off[RCH + 1]; ++e){
        const int i = sh.e.ilist[e];
        float F1, F2;
        if (e < PFL){ const float2 pf = sh.e.pfl[e]; F1 = pf.x; F2 = pf.y; }
        else        { F1 = g_F1[i]; F2 = g_F2[i]; }
        const float rz = 1.0f / fmaf(F1, za1, F2 * (zt2 - za2));
        float4 h;
        h.x = fmaf(F1, a1.x, F2 * (t2.x - a2.x)) * rz;
        h.y = fmaf(F1, a1.y, F2 * (t2.y - a2.y)) * rz;
        h.z = fmaf(F1, a1.z, F2 * (t2.z - a2.z)) * rz;
        h.w = fmaf(F1, a1.w, F2 * (t2.w - a2.w)) * rz;
        *(float4*)(out + (size_t)i * NDIM + tid * 4) = h;
      }
    }
  }
}

// ===================== fallback path: proven 5-kernel pipeline ===============
__global__ __launch_bounds__(256) void k_dots(const float* __restrict__ x,
                                              const float* __restrict__ w){
  const int wid = threadIdx.x >> 6, lane = threadIdx.x & 63;
  const int row = blockIdx.x * 4 + wid;
  const float* xr = x + (size_t)row * NDIM;
  float d1 = 0.f, d2 = 0.f;
  #pragma unroll
  for (int q = 0; q < 4; ++q){
    const int off = q * 256 + lane * 4;
    float4 X  = *(const float4*)(xr + off);
    float4 W1 = *(const float4*)(w + off);
    float4 W2 = *(const float4*)(w + NDIM + off);
    d1 = fmaf(X.x, W1.x, fmaf(X.y, W1.y, fmaf(X.z, W1.z, fmaf(X.w, W1.w, d1))));
    d2 = fmaf(X.x, W2.x, fmaf(X.y, W2.y, fmaf(X.z, W2.z, fmaf(X.w, W2.w, d2))));
  }
  #pragma unroll
  for (int m = 32; m >= 1; m >>= 1){
    d1 += __shfl_xor(d1, m, 64);
    d2 += __shfl_xor(d2, m, 64);
  }
  if (lane == 0){
    const float s1 = d1 * LOG2E, s2 = d2 * LOG2E;
    g_s1L[row] = s1;
    g_s2L[row] = s2;
    g_E[2 * row]     = __builtin_amdgcn_exp2f(s2);
    g_E[2 * row + 1] = __builtin_amdgcn_exp2f(ALPHA * s2);
    g_F1[row] = __builtin_amdgcn_exp2f(s1);
    g_F2[row] = __builtin_amdgcn_exp2f(ALPHA * s1);
  }
}

__global__ __launch_bounds__(256) void k_rank(){
  __shared__ __align__(16) float s2s[KDIM];
  const int tid = threadIdx.x;
  #pragma unroll
  for (int q = 0; q < 4; ++q)
    ((float4*)s2s)[q * 256 + tid] = ((const float4*)g_s2L)[q * 256 + tid];
  __syncthreads();
  const int grp = tid >> 4, sub = tid & 15;
  const int o = blockIdx.x * 16 + grp;
  int cnt = 0;
  if (o < KDIM){
    const float val = s2s[o];
    #pragma unroll 4
    for (int m = 0; m < 64; ++m){
      const int q4 = m * 16 + sub;
      const float4 v = ((const float4*)s2s)[q4];
      const int j0 = q4 * 4;
      cnt += (v.x > val || (v.x == val && (j0    ) < o));
      cnt += (v.y > val || (v.y == val && (j0 + 1) < o));
      cnt += (v.z > val || (v.z == val && (j0 + 2) < o));
      cnt += (v.w > val || (v.w == val && (j0 + 3) < o));
    }
  } else {
    const float thr = -g_s1L[o - KDIM];
    #pragma unroll 4
    for (int m = 0; m < 64; ++m){
      const int q4 = m * 16 + sub;
      const float4 v = ((const float4*)s2s)[q4];
      cnt += (v.x >= thr) + (v.y >= thr) + (v.z >= thr) + (v.w >= thr);
    }
  }
  cnt += __shfl_xor(cnt, 1, 64); cnt += __shfl_xor(cnt, 2, 64);
  cnt += __shfl_xor(cnt, 4, 64); cnt += __shfl_xor(cnt, 8, 64);
  if (sub == 0){
    if (o < KDIM) g_sig[cnt] = o;
    else          g_t[o - KDIM] = cnt;
  }
}

__global__ __launch_bounds__(256) void k_chunksum(const float* __restrict__ x){
  __shared__ int   js [RCH];
  __shared__ float e1s[RCH], e2s[RCH];
  const int c = blockIdx.x, tid = threadIdx.x;
  if (tid < RCH){
    const int j = g_sig[c * RCH + tid];
    js[tid]  = j;
    e1s[tid] = g_E[2 * j];
    e2s[tid] = g_E[2 * j + 1];
  }
  __syncthreads();
  if (tid == 0){
    float a = 0.f, b = 0.f;
    #pragma unroll
    for (int r = 0; r < RCH; ++r){ a += e1s[r]; b += e2s[r]; }
    g_cz[2 * c] = a; g_cz[2 * c + 1] = b;
  }
  float4 a1 = {0.f,0.f,0.f,0.f}, a2 = {0.f,0.f,0.f,0.f};
  #pragma unroll
  for (int r = 0; r < RCH; ++r){
    const float4 xv = *(const float4*)(x + (size_t)js[r] * NDIM + tid * 4);
    const float e1 = e1s[r], e2 = e2s[r];
    a1.x = fmaf(e1, xv.x, a1.x); a1.y = fmaf(e1, xv.y, a1.y);
    a1.z = fmaf(e1, xv.z, a1.z); a1.w = fmaf(e1, xv.w, a1.w);
    a2.x = fmaf(e2, xv.x, a2.x); a2.y = fmaf(e2, xv.y, a2.y);
    a2.z = fmaf(e2, xv.z, a2.z); a2.w = fmaf(e2, xv.w, a2.w);
  }
  *(float4*)&g_cs[c][tid * 4]        = a1;
  *(float4*)&g_cs[c][NDIM + tid * 4] = a2;
}

__global__ __launch_bounds__(256) void k_chunkscan(){
  __shared__ float TL[CCH][32];
  __shared__ float SS[8][32];
  const int tid = threadIdx.x;
  const int s = tid >> 5, k = tid & 31;
  const int col = blockIdx.x * 32 + k;
  float run = 0.f;
  #pragma unroll 8
  for (int m = 0; m < 32; ++m){
    const float v = g_cs[s * 32 + m][col];
    TL[s * 32 + m][k] = v;
    run += v;
  }
  SS[s][k] = run;
  __syncthreads();
  if (s == 0){
    float acc = 0.f;
    #pragma unroll
    for (int t = 0; t < 8; ++t){
      const float v = SS[t][k];
      SS[t][k] = acc;
      acc += v;
    }
    g_tot[col] = acc;
  }
  __syncthreads();
  run = SS[s][k];
  #pragma unroll 8
  for (int m = 0; m < 32; ++m){
    g_pre[s * 32 + m][col] = run;
    run += TL[s * 32 + m][k];
  }
  if (blockIdx.x == 0 && tid < 64){
    float v1[4], v2[4];
    #pragma unroll
    for (int q = 0; q < 4; ++q){
      v1[q] = g_cz[2 * (tid * 4 + q)];
      v2[q] = g_cz[2 * (tid * 4 + q) + 1];
    }
    const float s1 = v1[0] + v1[1] + v1[2] + v1[3];
    const float s2 = v2[0] + v2[1] + v2[2] + v2[3];
    float i1 = s1, i2 = s2;
    #pragma unroll
    for (int d = 1; d < 64; d <<= 1){
      const float t1 = __shfl_up(i1, d, 64);
      const float t2 = __shfl_up(i2, d, 64);
      if (tid >= d){ i1 += t1; i2 += t2; }
    }
    float e1 = i1 - s1, e2 = i2 - s2;
    #pragma unroll
    for (int q = 0; q < 4; ++q){
      g_zpre[2 * (tid * 4 + q)]     = e1;
      g_zpre[2 * (tid * 4 + q) + 1] = e2;
      e1 += v1[q]; e2 += v2[q];
    }
    if (tid == 63){ g_ztot[0] = e1; g_ztot[1] = e2; }
  }
}

__global__ __launch_bounds__(256) void k_emit(const float* __restrict__ x,
                                              float* __restrict__ out){
  __shared__ int    js [RCH];
  __shared__ float  e1s[RCH], e2s[RCH];
  __shared__ int    cnt[RCH + 1];
  __shared__ int    off[RCH + 2];
  __shared__ int    pos[RCH + 1];
  __shared__ int    ilist[KDIM];
  __shared__ float2 pfl[PFL];
  const int c = blockIdx.x, tid = threadIdx.x;
  const bool last = (c == CCH - 1);
  const int nbuck = last ? RCH + 1 : RCH;
  if (tid < RCH){
    const int j = g_sig[c * RCH + tid];
    js[tid]  = j;
    e1s[tid] = g_E[2 * j];
    e2s[tid] = g_E[2 * j + 1];
  }
  if (tid <= RCH) cnt[tid] = 0;
  __syncthreads();
  const int tbase = c * RCH;
  int myr[16];
  #pragma unroll
  for (int q = 0; q < 16; ++q){
    const int i = q * 256 + tid;
    const int t = g_t[i];
    const int r = t - tbase;
    const bool in = (r >= 0) && (r < nbuck);
    myr[q] = in ? r : -1;
    if (in) atomicAdd(&cnt[r], 1);
  }
  __syncthreads();
  if (tid == 0){
    int run = 0;
    #pragma unroll
    for (int r = 0; r <= RCH; ++r){
      const int v = cnt[r];
      off[r] = run; pos[r] = run;
      run += v;
    }
    off[RCH + 1] = run;
  }
  __syncthreads();
  #pragma unroll
  for (int q = 0; q < 16; ++q){
    if (myr[q] >= 0){
      const int i = q * 256 + tid;
      const int p = atomicAdd(&pos[myr[q]], 1);
      ilist[p] = i;
      if (p < PFL) pfl[p] = make_float2(g_F1[i], g_F2[i]);
    }
  }
  __syncthreads();

  float4 a1 = *(const float4*)&g_pre[c][tid * 4];
  float4 a2 = *(const float4*)&g_pre[c][NDIM + tid * 4];
  const float4 t2 = *(const float4*)&g_tot[NDIM + tid * 4];
  float za1 = g_zpre[2 * c], za2 = g_zpre[2 * c + 1];
  const float zt2 = g_ztot[1];
  float4 v[RCH];
  #pragma unroll
  for (int r = 0; r < RCH; ++r)
    v[r] = *(const float4*)(x + (size_t)js[r] * NDIM + tid * 4);

  #pragma unroll
  for (int r = 0; r < RCH; ++r){
    for (int e = off[r]; e < off[r + 1]; ++e){
      const int i = ilist[e];
      float F1, F2;
      if (e < PFL){ const float2 pf = pfl[e]; F1 = pf.x; F2 = pf.y; }
      else        { F1 = g_F1[i]; F2 = g_F2[i]; }
      const float rz = 1.0f / fmaf(F1, za1, F2 * (zt2 - za2));
      float4 h;
      h.x = fmaf(F1, a1.x, F2 * (t2.x - a2.x)) * rz;
      h.y = fmaf(F1, a1.y, F2 * (t2.y - a2.y)) * rz;
      h.z = fmaf(F1, a1.z, F2 * (t2.z - a2.z)) * rz;
      h.w = fmaf(F1, a1.w, F2 * (t2.w - a2.w)) * rz;
      *(float4*)(out + (size_t)i * NDIM + tid * 4) = h;
    }
    const float e1 = e1s[r], e2 = e2s[r];
    za1 += e1; za2 += e2;
    const float4 xv = v[r];
    a1.x = fmaf(e1, xv.x, a1.x); a1.y = fmaf(e1, xv.y, a1.y);
    a1.z = fmaf(e1, xv.z, a1.z); a1.w = fmaf(e1, xv.w, a1.w);
    a2.x = fmaf(e2, xv.x, a2.x); a2.y = fmaf(e2, xv.y, a2.y);
    a2.z = fmaf(e2, xv.z, a2.z); a2.w = fmaf(e2, xv.w, a2.w);
  }
  if (last){
    for (int e = off[RCH]; e < off[RCH + 1]; ++e){
      const int i = ilist[e];
      float F1, F2;
      if (e < PFL){ const float2 pf = pfl[e]; F1 = pf.x; F2 = pf.y; }
      else        { F1 = g_F1[i]; F2 = g_F2[i]; }
      const float rz = 1.0f / fmaf(F1, za1, F2 * (zt2 - za2));
      float4 h;
      h.x = fmaf(F1, a1.x, F2 * (t2.x - a2.x)) * rz;
      h.y = fmaf(F1, a1.y, F2 * (t2.y - a2.y)) * rz;
      h.z = fmaf(F1, a1.z, F2 * (t2.z - a2.z)) * rz;
      h.w = fmaf(F1, a1.w, F2 * (t2.w - a2.w)) * rz;
      *(float4*)(out + (size_t)i * NDIM + tid * 4) = h;
    }
  }
}

extern "C" void kernel_launch(void* const* d_in, const int* in_sizes, int n_in,
                              void* d_out, int out_size, void* d_ws, size_t ws_size,
                              hipStream_t stream){
  const float* x = (const float*)d_in[0];   // f32 (4096x1024)
  const float* w = (const float*)d_in[1];   // f32 (2048)
  float* out = (float*)d_out;               // f32 (4096x1024)
  (void)in_sizes; (void)n_in; (void)out_size; (void)d_ws; (void)ws_size;

  void* args[] = { (void*)&x, (void*)&w, (void*)&out };
  if (hipLaunchCooperativeKernel((const void*)k_fused, dim3(256), dim3(256),
                                 args, 0, stream) != hipSuccess){
    k_dots     <<<dim3(1024), dim3(256), 0, stream>>>(x, w);
    k_rank     <<<dim3(512),  dim3(256), 0, stream>>>();
    k_chunksum <<<dim3(CCH),  dim3(256), 0, stream>>>(x);
    k_chunkscan<<<dim3(64),   dim3(256), 0, stream>>>();
    k_emit     <<<dim3(CCH),  dim3(256), 0, stream>>>(x, out);
  }
}

// Round 4
// 116.599 us; speedup vs baseline: 2.8049x; 2.8049x over previous
//
#include <hip/hip_runtime.h>

#define KDIM 4096   // rows of x (= both i and j extents)
#define NDIM 1024   // feature dim
#define ALPHA 0.2f
#define LOG2E 1.4426950408889634f

// Sorted-prefix decomposition (exact): sort j by s2 desc (permutation sigma);
// sel(i,j) <=> rank(j) < t_i.
//   h_i = [F1_i*A1[t_i] + F2_i*(A2tot-A2[t_i])] / Z_i
//   Z_i =  F1_i*z1[t_i] + F2_i*(z2tot-z2[t_i])
__device__ __align__(16) float g_s1L[KDIM];
__device__ __align__(16) float g_s2L[KDIM];
__device__ __align__(16) float g_E [2 * KDIM];   // interleaved (E1_j, E2_j)
__device__ __align__(16) float g_F [2 * KDIM];   // interleaved (F1_i, F2_i)
__device__ __align__(16) int   g_t  [KDIM];      // t_i = #{j: s2_j >= -s1_i}
__device__ __align__(16) int   g_sig[KDIM];      // rank -> j

// ---- kernel 1: s1L/s2L = (x @ w1, x @ w2) * log2(e); row-local E/F. ----
__global__ __launch_bounds__(256) void k_dots(const float* __restrict__ x,
                                              const float* __restrict__ w){
  const int wid = threadIdx.x >> 6, lane = threadIdx.x & 63;
  const int row = blockIdx.x * 4 + wid;
  const float* xr = x + (size_t)row * NDIM;
  float d1 = 0.f, d2 = 0.f;
  #pragma unroll
  for (int q = 0; q < 4; ++q){
    const int off = q * 256 + lane * 4;
    float4 X  = *(const float4*)(xr + off);
    float4 W1 = *(const float4*)(w + off);
    float4 W2 = *(const float4*)(w + NDIM + off);
    d1 = fmaf(X.x, W1.x, fmaf(X.y, W1.y, fmaf(X.z, W1.z, fmaf(X.w, W1.w, d1))));
    d2 = fmaf(X.x, W2.x, fmaf(X.y, W2.y, fmaf(X.z, W2.z, fmaf(X.w, W2.w, d2))));
  }
  #pragma unroll
  for (int m = 32; m >= 1; m >>= 1){
    d1 += __shfl_xor(d1, m, 64);
    d2 += __shfl_xor(d2, m, 64);
  }
  if (lane == 0){
    const float s1 = d1 * LOG2E, s2 = d2 * LOG2E;
    g_s1L[row] = s1;
    g_s2L[row] = s2;
    g_E[2 * row]     = __builtin_amdgcn_exp2f(s2);
    g_E[2 * row + 1] = __builtin_amdgcn_exp2f(ALPHA * s2);
    g_F[2 * row]     = __builtin_amdgcn_exp2f(s1);
    g_F[2 * row + 1] = __builtin_amdgcn_exp2f(ALPHA * s1);
  }
}

// ---- kernel 2: ranks (stable desc sort of s2L via counting) + t_i counts. ----
__global__ __launch_bounds__(256) void k_rank(){
  __shared__ __align__(16) float s2s[KDIM];    // 16 KB
  const int tid = threadIdx.x;
  #pragma unroll
  for (int q = 0; q < 4; ++q)
    ((float4*)s2s)[q * 256 + tid] = ((const float4*)g_s2L)[q * 256 + tid];
  __syncthreads();
  const int grp = tid >> 4, sub = tid & 15;
  const int o = blockIdx.x * 16 + grp;         // 0..8191
  int cnt = 0;
  if (o < KDIM){
    const float val = s2s[o];
    #pragma unroll 4
    for (int m = 0; m < 64; ++m){
      const int q4 = m * 16 + sub;
      const float4 v = ((const float4*)s2s)[q4];
      const int j0 = q4 * 4;
      cnt += (v.x > val || (v.x == val && (j0    ) < o));
      cnt += (v.y > val || (v.y == val && (j0 + 1) < o));
      cnt += (v.z > val || (v.z == val && (j0 + 2) < o));
      cnt += (v.w > val || (v.w == val && (j0 + 3) < o));
    }
  } else {
    const float thr = -g_s1L[o - KDIM];
    #pragma unroll 4
    for (int m = 0; m < 64; ++m){
      const int q4 = m * 16 + sub;
      const float4 v = ((const float4*)s2s)[q4];
      cnt += (v.x >= thr) + (v.y >= thr) + (v.z >= thr) + (v.w >= thr);
    }
  }
  cnt += __shfl_xor(cnt, 1, 64); cnt += __shfl_xor(cnt, 2, 64);
  cnt += __shfl_xor(cnt, 4, 64); cnt += __shfl_xor(cnt, 8, 64);
  if (sub == 0){
    if (o < KDIM) g_sig[cnt] = o;
    else          g_t[o - KDIM] = cnt;
  }
}

// ---- kernel 3: column-partitioned full scan + emit. 256 blocks x 256 thr. ----
// Block owns 4 columns (XCD-swizzled so 8 blocks sharing a 128B x-line sit on
// one XCD's L2). Thread t owns ranks [16t,16t+16): seg-sums 10 running values
// (4xA1, 4xA2, z1, z2), block-scans them, buckets all 4096 outputs by t_i in
// LDS, then walks its 16 ranks emitting bucketed outputs with the live prefix.
// __launch_bounds__(256,1): v[16]+e1/e2+scan state ~180 VGPR must NOT spill
// (round-3 post-mortem: default bounds capped VGPR at 60 -> 32 MB scratch).
__global__ __launch_bounds__(256, 1) void k_scanemit(const float* __restrict__ x,
                                                     float* __restrict__ out){
  __shared__ int   off [KDIM + 2];    // hist -> exclusive offsets (bins 0..4096)
  __shared__ int   pos [KDIM + 1];
  __shared__ int   ilist[KDIM];
  __shared__ float wscan[4][10];
  __shared__ int   iws[4];
  const int tid = threadIdx.x, lane = tid & 63, wv = tid >> 6;
  const int cg = ((blockIdx.x & 7) << 5) + (blockIdx.x >> 3);   // XCD-local cols
  const int c0 = cg * 4;

  for (int b = tid; b < KDIM + 2; b += 256) off[b] = 0;

  // per-thread rank data: sorted row ids, E pairs, x fragments (issued early)
  int js[16];
  #pragma unroll
  for (int q = 0; q < 4; ++q){
    const int4 j4 = ((const int4*)g_sig)[tid * 4 + q];
    js[q*4+0] = j4.x; js[q*4+1] = j4.y; js[q*4+2] = j4.z; js[q*4+3] = j4.w;
  }
  float e1[16], e2[16];
  #pragma unroll
  for (int r = 0; r < 16; ++r){
    const float2 e = *(const float2*)&g_E[2 * js[r]];
    e1[r] = e.x; e2[r] = e.y;
  }
  float4 v[16];
  #pragma unroll
  for (int r = 0; r < 16; ++r)
    v[r] = *(const float4*)(x + (size_t)js[r] * NDIM + c0);

  // per-thread t values for outputs i = tid*16 .. tid*16+15
  int tv[16];
  #pragma unroll
  for (int q = 0; q < 4; ++q){
    const int4 t4 = ((const int4*)g_t)[tid * 4 + q];
    tv[q*4+0] = t4.x; tv[q*4+1] = t4.y; tv[q*4+2] = t4.z; tv[q*4+3] = t4.w;
  }
  __syncthreads();                              // off[] zeroed
  #pragma unroll
  for (int r = 0; r < 16; ++r) atomicAdd(&off[tv[r]], 1);
  __syncthreads();

  // exclusive scan of histogram (bins 0..4095 thread-owned; 4096 special)
  int loc[16], myc = 0;
  #pragma unroll
  for (int r = 0; r < 16; ++r){ loc[r] = off[tid * 16 + r]; myc += loc[r]; }
  int inc = myc;
  #pragma unroll
  for (int d = 1; d < 64; d <<= 1){
    const int tmp = __shfl_up(inc, d, 64);
    if (lane >= d) inc += tmp;
  }
  if (lane == 63) iws[wv] = inc;
  __syncthreads();
  int wpre = 0;
  #pragma unroll
  for (int w2 = 0; w2 < 4; ++w2) if (w2 < wv) wpre += iws[w2];
  int run = wpre + inc - myc;
  #pragma unroll
  for (int r = 0; r < 16; ++r){ const int cc = loc[r]; off[tid * 16 + r] = run; run += cc; }
  if (tid == 255){ off[KDIM] = run; off[KDIM + 1] = KDIM; }
  __syncthreads();
  for (int b = tid; b < KDIM + 1; b += 256) pos[b] = off[b];
  __syncthreads();
  #pragma unroll
  for (int r = 0; r < 16; ++r){
    const int p = atomicAdd(&pos[tv[r]], 1);
    ilist[p] = tid * 16 + r;
  }

  // segment sums of the 10 running values over this thread's 16 ranks
  float s[10] = {0,0,0,0,0,0,0,0,0,0};
  #pragma unroll
  for (int r = 0; r < 16; ++r){
    s[0] = fmaf(e1[r], v[r].x, s[0]); s[1] = fmaf(e1[r], v[r].y, s[1]);
    s[2] = fmaf(e1[r], v[r].z, s[2]); s[3] = fmaf(e1[r], v[r].w, s[3]);
    s[4] = fmaf(e2[r], v[r].x, s[4]); s[5] = fmaf(e2[r], v[r].y, s[5]);
    s[6] = fmaf(e2[r], v[r].z, s[6]); s[7] = fmaf(e2[r], v[r].w, s[7]);
    s[8] += e1[r]; s[9] += e2[r];
  }
  float a[10];
  #pragma unroll
  for (int k = 0; k < 10; ++k) a[k] = s[k];
  #pragma unroll
  for (int d = 1; d < 64; d <<= 1){
    float tmp[10];
    #pragma unroll
    for (int k = 0; k < 10; ++k) tmp[k] = __shfl_up(a[k], d, 64);
    if (lane >= d){
      #pragma unroll
      for (int k = 0; k < 10; ++k) a[k] += tmp[k];
    }
  }
  if (lane == 63){
    #pragma unroll
    for (int k = 0; k < 10; ++k) wscan[wv][k] = a[k];
  }
  __syncthreads();                 // wscan ready; also orders ilist scatter
  float ex[10], tot[10];
  #pragma unroll
  for (int k = 0; k < 10; ++k){
    float wp = 0.f, tt = 0.f;
    #pragma unroll
    for (int w2 = 0; w2 < 4; ++w2){
      const float vv = wscan[w2][k];
      tt += vv;
      if (w2 < wv) wp += vv;
    }
    ex[k]  = wp + a[k] - s[k];     // exclusive prefix at rank 16*tid
    tot[k] = tt;
  }
  float4 a1 = make_float4(ex[0], ex[1], ex[2], ex[3]);
  float4 a2 = make_float4(ex[4], ex[5], ex[6], ex[7]);
  float za1 = ex[8], za2 = ex[9];
  const float4 t1 = make_float4(tot[0], tot[1], tot[2], tot[3]);
  const float4 t2 = make_float4(tot[4], tot[5], tot[6], tot[7]);
  const float zt1 = tot[8], zt2 = tot[9];

  // walk 16 ranks: emit bucket p before adding rank p's row
  #pragma unroll
  for (int r = 0; r < 16; ++r){
    const int p = tid * 16 + r;
    for (int e = off[p]; e < off[p + 1]; ++e){
      const int i = ilist[e];
      const float2 Fp = *(const float2*)&g_F[2 * i];
      const float F1 = Fp.x, F2 = Fp.y;
      const float rz = 1.0f / fmaf(F1, za1, F2 * (zt2 - za2));
      float4 h;
      h.x = fmaf(F1, a1.x, F2 * (t2.x - a2.x)) * rz;
      h.y = fmaf(F1, a1.y, F2 * (t2.y - a2.y)) * rz;
      h.z = fmaf(F1, a1.z, F2 * (t2.z - a2.z)) * rz;
      h.w = fmaf(F1, a1.w, F2 * (t2.w - a2.w)) * rz;
      *(float4*)(out + (size_t)i * NDIM + c0) = h;
    }
    za1 += e1[r]; za2 += e2[r];
    a1.x = fmaf(e1[r], v[r].x, a1.x); a1.y = fmaf(e1[r], v[r].y, a1.y);
    a1.z = fmaf(e1[r], v[r].z, a1.z); a1.w = fmaf(e1[r], v[r].w, a1.w);
    a2.x = fmaf(e2[r], v[r].x, a2.x); a2.y = fmaf(e2[r], v[r].y, a2.y);
    a2.z = fmaf(e2[r], v[r].z, a2.z); a2.w = fmaf(e2[r], v[r].w, a2.w);
  }

  // bin t=4096 (fully selected rows): prefix = totals, Z = F1*zt1
  const float rzz = 1.0f / zt1;
  for (int e = off[KDIM] + tid; e < KDIM; e += 256){
    const int i = ilist[e];
    float4 h;
    h.x = t1.x * rzz; h.y = t1.y * rzz; h.z = t1.z * rzz; h.w = t1.w * rzz;
    *(float4*)(out + (size_t)i * NDIM + c0) = h;
  }
}

extern "C" void kernel_launch(void* const* d_in, const int* in_sizes, int n_in,
                              void* d_out, int out_size, void* d_ws, size_t ws_size,
                              hipStream_t stream){
  const float* x = (const float*)d_in[0];   // f32 (4096x1024)
  const float* w = (const float*)d_in[1];   // f32 (2048)
  float* out = (float*)d_out;               // f32 (4096x1024)
  (void)in_sizes; (void)n_in; (void)out_size; (void)d_ws; (void)ws_size;

  k_dots    <<<dim3(1024), dim3(256), 0, stream>>>(x, w);
  k_rank    <<<dim3(512),  dim3(256), 0, stream>>>();
  k_scanemit<<<dim3(256),  dim3(256), 0, stream>>>(x, out);
}